// Round 3
// baseline (1643.562 us; speedup 1.0000x reference)
//
#include <hip/hip_runtime.h>

constexpr int H  = 16;
constexpr int HD = 48;
constexpr int D  = 768;    // H*HD
constexpr int DZ = 128;
constexpr int S  = 1024;
constexpr float EPS = 1e-5f;

__device__ __forceinline__ float sigmoidf_(float x) { return 1.f / (1.f + __expf(-x)); }

// ---------------------------------------------------------------------------
// Tiled f32 GEMM body: C[m][n] = sum_k A[m][k] * W[n][k]  (+bias[n], A gated by
// sigmoid(G) if G != nullptr). BM=BN=64, BK=16, 256 threads, 4x4 micro-tile.
// ---------------------------------------------------------------------------
__device__ __forceinline__ void gemm_tile(const float* __restrict__ A,
                                          const float* __restrict__ G,
                                          const float* __restrict__ W,
                                          const float* __restrict__ bias,
                                          float* __restrict__ C,
                                          const int bm, const int bn,
                                          const int N, const int K) {
  __shared__ float As[16][68];   // [k][m], row stride 68 floats (16B-aligned rows)
  __shared__ float Bs[16][68];   // [k][n]
  const int tid = threadIdx.x;
  const int tx = tid & 15, ty = tid >> 4;
  const int lr = tid >> 2;          // 0..63 tile row
  const int lk = (tid & 3) << 2;    // 0,4,8,12
  float acc[4][4] = {};
  for (int k0 = 0; k0 < K; k0 += 16) {
    float4 a = *reinterpret_cast<const float4*>(A + (size_t)(bm + lr) * K + (k0 + lk));
    if (G) {
      const float4 g = *reinterpret_cast<const float4*>(G + (size_t)(bm + lr) * K + (k0 + lk));
      a.x *= sigmoidf_(g.x); a.y *= sigmoidf_(g.y);
      a.z *= sigmoidf_(g.z); a.w *= sigmoidf_(g.w);
    }
    const float4 b = *reinterpret_cast<const float4*>(W + (size_t)(bn + lr) * K + (k0 + lk));
    As[lk + 0][lr] = a.x; As[lk + 1][lr] = a.y; As[lk + 2][lr] = a.z; As[lk + 3][lr] = a.w;
    Bs[lk + 0][lr] = b.x; Bs[lk + 1][lr] = b.y; Bs[lk + 2][lr] = b.z; Bs[lk + 3][lr] = b.w;
    __syncthreads();
#pragma unroll
    for (int k = 0; k < 16; ++k) {
      const float4 av = *reinterpret_cast<const float4*>(&As[k][ty << 2]);
      const float4 bv = *reinterpret_cast<const float4*>(&Bs[k][tx << 2]);
      const float am[4] = {av.x, av.y, av.z, av.w};
      const float bb[4] = {bv.x, bv.y, bv.z, bv.w};
#pragma unroll
      for (int i = 0; i < 4; ++i)
#pragma unroll
        for (int j = 0; j < 4; ++j) acc[i][j] += am[i] * bb[j];
    }
    __syncthreads();
  }
  float4 badd = make_float4(0.f, 0.f, 0.f, 0.f);
  if (bias) badd = *reinterpret_cast<const float4*>(bias + bn + (tx << 2));
#pragma unroll
  for (int i = 0; i < 4; ++i) {
    const int m = bm + (ty << 2) + i;
    float4 r;
    r.x = acc[i][0] + badd.x; r.y = acc[i][1] + badd.y;
    r.z = acc[i][2] + badd.z; r.w = acc[i][3] + badd.w;
    *reinterpret_cast<float4*>(C + (size_t)m * N + bn + (tx << 2)) = r;
  }
}

// Fused q/k/v/g projection: grid.x selects weight (4 x D/64), grid.y = S/64.
__global__ __launch_bounds__(256)
void qkvg_kernel(const float* __restrict__ s, const float* __restrict__ Wq,
                 const float* __restrict__ bq, const float* __restrict__ Wk,
                 const float* __restrict__ Wv, const float* __restrict__ Wg,
                 float* __restrict__ out) {
  const int nb = D / 64;
  const int wsel = blockIdx.x / nb;
  const int bn = (blockIdx.x % nb) * 64;
  const int bm = blockIdx.y * 64;
  const float* W = (wsel == 0) ? Wq : (wsel == 1) ? Wk : (wsel == 2) ? Wv : Wg;
  const float* bias = (wsel == 0) ? bq : nullptr;
  float* C = out + (size_t)wsel * S * D;
  gemm_tile(s, nullptr, W, bias, C, bm, bn, D, D);
}

// Gated output projection: out = (o * sigmoid(g)) @ Wo^T
__global__ __launch_bounds__(256)
void outproj_kernel(const float* __restrict__ o, const float* __restrict__ g,
                    const float* __restrict__ Wo, float* __restrict__ out) {
  gemm_tile(o, g, Wo, nullptr, out, blockIdx.y * 64, blockIdx.x * 64, D, D);
}

// ---------------------------------------------------------------------------
// pair-bias prep: WzW[h][c] = Wz[h][c]*ln_w[c]; S1[h] = sum_c WzW; S2[h] =
// sum_c ln_b[c]*Wz[h][c].  One small block.
// ---------------------------------------------------------------------------
__global__ __launch_bounds__(256)
void pb_prep_kernel(const float* __restrict__ Wz, const float* __restrict__ ln_w,
                    const float* __restrict__ ln_b, float* __restrict__ wzw,
                    float* __restrict__ s12) {
  const int t = threadIdx.x;
  for (int e = t; e < 16 * DZ; e += 256) wzw[e] = Wz[e] * ln_w[e & 127];
  if (t < 32) {
    const int h = t & 15;
    const float* coef = (t < 16) ? ln_w : ln_b;
    float a = 0.f;
    for (int c = 0; c < DZ; ++c) a += Wz[h * DZ + c] * coef[c];
    s12[t] = a;
  }
}

// ---------------------------------------------------------------------------
// Pair bias v2: bias[h][s][t] = inv*(dot(z_row, WzW[h]) - mu*S1[h]) + S2[h].
// 16 lanes per z-row (lane owns 8 c's); weights in 128 VGPRs loaded once;
// no LDS staging. Per wave: 16-row chunk, 4 quads of 4 rows. acc[16] reduced
// across the 16-lane group via tree-halving (lands h=bitrev(sub) per lane);
// 16x16 result tile transposed through 1KB LDS -> float4 writes per h-plane.
// ---------------------------------------------------------------------------
__global__ __launch_bounds__(256)
void pair_bias_kernel(const float* __restrict__ z, const float* __restrict__ wzw,
                      const float* __restrict__ s12, float* __restrict__ bias_out) {
  __shared__ float T[4][16][17];
  const int lane = threadIdx.x & 63;
  const int wv = threadIdx.x >> 6;
  const int sub = lane & 15;
  const int g = lane >> 4;
  const int hrev = ((sub & 1) << 3) | ((sub & 2) << 1) | ((sub & 4) >> 1) | ((sub & 8) >> 3);

  // per-lane weight slice: w[h][k] for c = sub*8 + k
  float4 wA[16], wB[16];
#pragma unroll
  for (int h = 0; h < 16; ++h) {
    wA[h] = *reinterpret_cast<const float4*>(wzw + h * DZ + sub * 8);
    wB[h] = *reinterpret_cast<const float4*>(wzw + h * DZ + sub * 8 + 4);
  }
  const float S1l = s12[hrev];
  const float S2l = s12[16 + hrev];

  const int wave_id = blockIdx.x * 4 + wv;
  const int nwaves = gridDim.x * 4;
  const int nchunks = (S * S) / 16;

  for (int chunk = wave_id; chunk < nchunks; chunk += nwaves) {
    const size_t p0 = (size_t)chunk * 16;
    const float* rp = z + (p0 + g) * DZ + sub * 8;
    float4 za[4], zb[4];
#pragma unroll
    for (int q = 0; q < 4; ++q) {
      za[q] = *reinterpret_cast<const float4*>(rp + (size_t)q * 4 * DZ);
      zb[q] = *reinterpret_cast<const float4*>(rp + (size_t)q * 4 * DZ + 4);
    }
#pragma unroll
    for (int q = 0; q < 4; ++q) {
      float s1 = za[q].x + za[q].y + za[q].z + za[q].w +
                 zb[q].x + zb[q].y + zb[q].z + zb[q].w;
      float s2 = za[q].x * za[q].x + za[q].y * za[q].y + za[q].z * za[q].z +
                 za[q].w * za[q].w + zb[q].x * zb[q].x + zb[q].y * zb[q].y +
                 zb[q].z * zb[q].z + zb[q].w * zb[q].w;
      float acc[16];
#pragma unroll
      for (int h = 0; h < 16; ++h) {
        acc[h] = za[q].x * wA[h].x + za[q].y * wA[h].y + za[q].z * wA[h].z +
                 za[q].w * wA[h].w + zb[q].x * wB[h].x + zb[q].y * wB[h].y +
                 zb[q].z * wB[h].z + zb[q].w * wB[h].w;
      }
      // butterfly all-reduce of (s1,s2) within 16-lane group
#pragma unroll
      for (int m = 1; m <= 8; m <<= 1) {
        s1 += __shfl_xor(s1, m);
        s2 += __shfl_xor(s2, m);
      }
      // tree-halving reduce of acc[16]: lane ends with h = bitrev4(sub)
#pragma unroll
      for (int step = 0; step < 4; ++step) {
        const int m = 1 << step;
        const int half = 8 >> step;
        const bool up = (sub & m) != 0;
#pragma unroll
        for (int i = 0; i < half; ++i) {
          const float keep = up ? acc[i + half] : acc[i];
          const float give = up ? acc[i] : acc[i + half];
          acc[i] = keep + __shfl_xor(give, m);
        }
      }
      const float mu = s1 * (1.f / DZ);
      const float var = s2 * (1.f / DZ) - mu * mu;
      const float inv = rsqrtf(var + EPS);
      T[wv][hrev][q * 4 + g] = inv * (acc[0] - mu * S1l) + S2l;
    }
    // intra-wave transpose read (no barrier needed: same wave) + global write
    const float4 o4 = *reinterpret_cast<const float4*>(&T[wv][lane >> 2][(lane & 3) * 4]);
    *reinterpret_cast<float4*>(bias_out + (size_t)(lane >> 2) * S * S + p0 + (lane & 3) * 4) = o4;
  }
}

// ---------------------------------------------------------------------------
// Flash-style attention. Block = (head h, 64 query rows), 256 threads (16x16).
// ---------------------------------------------------------------------------
__global__ __launch_bounds__(256)
void attn_kernel(const float* __restrict__ q_ws, const float* __restrict__ k_ws,
                 const float* __restrict__ v_ws, const float* __restrict__ bias,
                 float* __restrict__ o_ws) {
  __shared__ float Qs[64][52];   // query rows (scaled), padded
  __shared__ float Ks[64][52];   // key rows, padded
  __shared__ float Vt[48][68];   // V transposed [d][t]
  __shared__ float Ps[64][68];   // probabilities tile

  const int tid = threadIdx.x;
  const int tx = tid & 15, ty = tid >> 4;
  const int h  = blockIdx.x >> 4;
  const int q0 = (blockIdx.x & 15) << 6;
  const float scale = 0.14433756729740643f;  // 1/sqrt(48)

  // stage Q (scaled): 64 rows x 12 float4
#pragma unroll
  for (int i = 0; i < 3; ++i) {
    const int f4 = tid + i * 256;
    const int r = f4 / 12, c4 = f4 % 12;
    float4 v = *reinterpret_cast<const float4*>(q_ws + (size_t)(q0 + r) * D + h * HD + c4 * 4);
    v.x *= scale; v.y *= scale; v.z *= scale; v.w *= scale;
    *reinterpret_cast<float4*>(&Qs[r][c4 * 4]) = v;
  }

  float m[4], l[4] = {0.f, 0.f, 0.f, 0.f};
  float acc[4][3] = {};
#pragma unroll
  for (int i = 0; i < 4; ++i) m[i] = -1e30f;

  for (int t0 = 0; t0 < S; t0 += 64) {
    // stage K tile (rows) and V tile (transposed)
#pragma unroll
    for (int i = 0; i < 3; ++i) {
      const int f4 = tid + i * 256;
      const int r = f4 / 12, c4 = f4 % 12;
      const float4 kv = *reinterpret_cast<const float4*>(k_ws + (size_t)(t0 + r) * D + h * HD + c4 * 4);
      *reinterpret_cast<float4*>(&Ks[r][c4 * 4]) = kv;
      const float4 vv = *reinterpret_cast<const float4*>(v_ws + (size_t)(t0 + r) * D + h * HD + c4 * 4);
      Vt[c4 * 4 + 0][r] = vv.x; Vt[c4 * 4 + 1][r] = vv.y;
      Vt[c4 * 4 + 2][r] = vv.z; Vt[c4 * 4 + 3][r] = vv.w;
    }
    __syncthreads();

    // S-tile: rows 4ty+i, cols 4tx+j, init from bias
    float s4[4][4];
#pragma unroll
    for (int i = 0; i < 4; ++i) {
      const float4 b4 = *reinterpret_cast<const float4*>(
          bias + ((size_t)h * S + (q0 + 4 * ty + i)) * S + t0 + 4 * tx);
      s4[i][0] = b4.x; s4[i][1] = b4.y; s4[i][2] = b4.z; s4[i][3] = b4.w;
    }
#pragma unroll
    for (int k4 = 0; k4 < 12; ++k4) {
      float4 qv[4], kv[4];
#pragma unroll
      for (int i = 0; i < 4; ++i) qv[i] = *reinterpret_cast<const float4*>(&Qs[4 * ty + i][k4 * 4]);
#pragma unroll
      for (int j = 0; j < 4; ++j) kv[j] = *reinterpret_cast<const float4*>(&Ks[4 * tx + j][k4 * 4]);
#pragma unroll
      for (int i = 0; i < 4; ++i)
#pragma unroll
        for (int j = 0; j < 4; ++j)
          s4[i][j] += qv[i].x * kv[j].x + qv[i].y * kv[j].y +
                      qv[i].z * kv[j].z + qv[i].w * kv[j].w;
    }

    // online softmax (row groups = 16 tx lanes; shfl_xor stays in-group)
#pragma unroll
    for (int i = 0; i < 4; ++i) {
      float tmax = fmaxf(fmaxf(s4[i][0], s4[i][1]), fmaxf(s4[i][2], s4[i][3]));
#pragma unroll
      for (int off = 8; off >= 1; off >>= 1) tmax = fmaxf(tmax, __shfl_xor(tmax, off));
      const float mn = fmaxf(m[i], tmax);
      const float fac = __expf(m[i] - mn);
      float p0 = __expf(s4[i][0] - mn), p1 = __expf(s4[i][1] - mn);
      float p2 = __expf(s4[i][2] - mn), p3 = __expf(s4[i][3] - mn);
      l[i] = l[i] * fac + (p0 + p1 + p2 + p3);   // per-thread partial sum
      acc[i][0] *= fac; acc[i][1] *= fac; acc[i][2] *= fac;
      m[i] = mn;
      *reinterpret_cast<float4*>(&Ps[4 * ty + i][4 * tx]) = make_float4(p0, p1, p2, p3);
    }
    __syncthreads();

    // PV: rows 4ty+i, dims 3tx+j, vectorized over t-quads
#pragma unroll
    for (int t4 = 0; t4 < 16; ++t4) {
      float4 pv[4], vv[3];
#pragma unroll
      for (int i = 0; i < 4; ++i) pv[i] = *reinterpret_cast<const float4*>(&Ps[4 * ty + i][4 * t4]);
#pragma unroll
      for (int j = 0; j < 3; ++j) vv[j] = *reinterpret_cast<const float4*>(&Vt[3 * tx + j][4 * t4]);
#pragma unroll
      for (int i = 0; i < 4; ++i)
#pragma unroll
        for (int j = 0; j < 3; ++j)
          acc[i][j] += pv[i].x * vv[j].x + pv[i].y * vv[j].y +
                       pv[i].z * vv[j].z + pv[i].w * vv[j].w;
    }
    __syncthreads();
  }

  // finalize: full row sum of l across tx group, normalize, write
#pragma unroll
  for (int i = 0; i < 4; ++i) {
    float lt = l[i];
#pragma unroll
    for (int off = 8; off >= 1; off >>= 1) lt += __shfl_xor(lt, off);
    const float rl = 1.f / lt;
    float* op = o_ws + (size_t)(q0 + 4 * ty + i) * D + h * HD;
#pragma unroll
    for (int j = 0; j < 3; ++j) op[3 * tx + j] = acc[i][j] * rl;
  }
}

extern "C" void kernel_launch(void* const* d_in, const int* in_sizes, int n_in,
                              void* d_out, int out_size, void* d_ws, size_t ws_size,
                              hipStream_t stream) {
  const float* s    = (const float*)d_in[0];
  const float* z    = (const float*)d_in[1];
  const float* Wq   = (const float*)d_in[2];
  const float* bq   = (const float*)d_in[3];
  const float* Wk   = (const float*)d_in[4];
  const float* Wv   = (const float*)d_in[5];
  const float* Wg   = (const float*)d_in[6];
  const float* ln_w = (const float*)d_in[7];
  const float* ln_b = (const float*)d_in[8];
  const float* Wz   = (const float*)d_in[9];
  const float* Wo   = (const float*)d_in[10];
  float* out = (float*)d_out;

  // workspace (floats): q,k,v,g,o = 5*S*D; bias = H*S*S; wzw = 2048; s12 = 32
  float* q_ws    = (float*)d_ws;
  float* k_ws    = q_ws + (size_t)S * D;
  float* v_ws    = k_ws + (size_t)S * D;
  float* g_ws    = v_ws + (size_t)S * D;
  float* o_ws    = g_ws + (size_t)S * D;
  float* bias_ws = o_ws + (size_t)S * D;
  float* wzw_ws  = bias_ws + (size_t)H * S * S;
  float* s12_ws  = wzw_ws + 16 * DZ;

  // 1) fused QKVG projections
  qkvg_kernel<<<dim3(4 * (D / 64), S / 64), 256, 0, stream>>>(s, Wq, bq, Wk, Wv, Wg, q_ws);
  // 2) pair bias (LN folded): prep then streaming kernel
  pb_prep_kernel<<<1, 256, 0, stream>>>(Wz, ln_w, ln_b, wzw_ws, s12_ws);
  pair_bias_kernel<<<2048, 256, 0, stream>>>(z, wzw_ws, s12_ws, bias_ws);
  // 3) flash attention
  attn_kernel<<<dim3(H * (S / 64)), 256, 0, stream>>>(q_ws, k_ws, v_ws, bias_ws, o_ws);
  // 4) gate + output projection
  outproj_kernel<<<dim3(D / 64, S / 64), 256, 0, stream>>>(o_ws, g_ws, Wo, out);
}

// Round 4
// 441.695 us; speedup vs baseline: 3.7210x; 3.7210x over previous
//
#include <hip/hip_runtime.h>

constexpr int H  = 16;
constexpr int HD = 48;
constexpr int D  = 768;    // H*HD
constexpr int DZ = 128;
constexpr int S  = 1024;
constexpr float EPS = 1e-5f;

__device__ __forceinline__ float sigmoidf_(float x) { return 1.f / (1.f + __expf(-x)); }

// ---------------------------------------------------------------------------
// Tiled f32 GEMM body: C[m][n] = sum_k A[m][k] * W[n][k]  (+bias[n], A gated by
// sigmoid(G) if G != nullptr). BM=BN=64, BK=16, 256 threads, 4x4 micro-tile.
// ---------------------------------------------------------------------------
__device__ __forceinline__ void gemm_tile(const float* __restrict__ A,
                                          const float* __restrict__ G,
                                          const float* __restrict__ W,
                                          const float* __restrict__ bias,
                                          float* __restrict__ C,
                                          const int bm, const int bn,
                                          const int N, const int K) {
  __shared__ float As[16][68];   // [k][m], row stride 68 floats (16B-aligned rows)
  __shared__ float Bs[16][68];   // [k][n]
  const int tid = threadIdx.x;
  const int tx = tid & 15, ty = tid >> 4;
  const int lr = tid >> 2;          // 0..63 tile row
  const int lk = (tid & 3) << 2;    // 0,4,8,12
  float acc[4][4] = {};
  for (int k0 = 0; k0 < K; k0 += 16) {
    float4 a = *reinterpret_cast<const float4*>(A + (size_t)(bm + lr) * K + (k0 + lk));
    if (G) {
      const float4 g = *reinterpret_cast<const float4*>(G + (size_t)(bm + lr) * K + (k0 + lk));
      a.x *= sigmoidf_(g.x); a.y *= sigmoidf_(g.y);
      a.z *= sigmoidf_(g.z); a.w *= sigmoidf_(g.w);
    }
    const float4 b = *reinterpret_cast<const float4*>(W + (size_t)(bn + lr) * K + (k0 + lk));
    As[lk + 0][lr] = a.x; As[lk + 1][lr] = a.y; As[lk + 2][lr] = a.z; As[lk + 3][lr] = a.w;
    Bs[lk + 0][lr] = b.x; Bs[lk + 1][lr] = b.y; Bs[lk + 2][lr] = b.z; Bs[lk + 3][lr] = b.w;
    __syncthreads();
#pragma unroll
    for (int k = 0; k < 16; ++k) {
      const float4 av = *reinterpret_cast<const float4*>(&As[k][ty << 2]);
      const float4 bv = *reinterpret_cast<const float4*>(&Bs[k][tx << 2]);
      const float am[4] = {av.x, av.y, av.z, av.w};
      const float bb[4] = {bv.x, bv.y, bv.z, bv.w};
#pragma unroll
      for (int i = 0; i < 4; ++i)
#pragma unroll
        for (int j = 0; j < 4; ++j) acc[i][j] += am[i] * bb[j];
    }
    __syncthreads();
  }
  float4 badd = make_float4(0.f, 0.f, 0.f, 0.f);
  if (bias) badd = *reinterpret_cast<const float4*>(bias + bn + (tx << 2));
#pragma unroll
  for (int i = 0; i < 4; ++i) {
    const int m = bm + (ty << 2) + i;
    float4 r;
    r.x = acc[i][0] + badd.x; r.y = acc[i][1] + badd.y;
    r.z = acc[i][2] + badd.z; r.w = acc[i][3] + badd.w;
    *reinterpret_cast<float4*>(C + (size_t)m * N + bn + (tx << 2)) = r;
  }
}

// Fused q/k/v/g projection: grid.x selects weight (4 x D/64), grid.y = S/64.
__global__ __launch_bounds__(256)
void qkvg_kernel(const float* __restrict__ s, const float* __restrict__ Wq,
                 const float* __restrict__ bq, const float* __restrict__ Wk,
                 const float* __restrict__ Wv, const float* __restrict__ Wg,
                 float* __restrict__ out) {
  const int nb = D / 64;
  const int wsel = blockIdx.x / nb;
  const int bn = (blockIdx.x % nb) * 64;
  const int bm = blockIdx.y * 64;
  const float* W = (wsel == 0) ? Wq : (wsel == 1) ? Wk : (wsel == 2) ? Wv : Wg;
  const float* bias = (wsel == 0) ? bq : nullptr;
  float* C = out + (size_t)wsel * S * D;
  gemm_tile(s, nullptr, W, bias, C, bm, bn, D, D);
}

// Gated output projection: out = (o * sigmoid(g)) @ Wo^T
__global__ __launch_bounds__(256)
void outproj_kernel(const float* __restrict__ o, const float* __restrict__ g,
                    const float* __restrict__ Wo, float* __restrict__ out) {
  gemm_tile(o, g, Wo, nullptr, out, blockIdx.y * 64, blockIdx.x * 64, D, D);
}

// ---------------------------------------------------------------------------
// pair-bias prep: WzW[h][c] = Wz[h][c]*ln_w[c]; S1[h] = sum_c WzW; S2[h] =
// sum_c ln_b[c]*Wz[h][c].  One small block.
// ---------------------------------------------------------------------------
__global__ __launch_bounds__(256)
void pb_prep_kernel(const float* __restrict__ Wz, const float* __restrict__ ln_w,
                    const float* __restrict__ ln_b, float* __restrict__ wzw,
                    float* __restrict__ s12) {
  const int t = threadIdx.x;
  for (int e = t; e < 16 * DZ; e += 256) wzw[e] = Wz[e] * ln_w[e & 127];
  if (t < 32) {
    const int h = t & 15;
    const float* coef = (t < 16) ? ln_w : ln_b;
    float a = 0.f;
    for (int c = 0; c < DZ; ++c) a += Wz[h * DZ + c] * coef[c];
    s12[t] = a;
  }
}

// ---------------------------------------------------------------------------
// Pair bias v3: shuffle-free. Each lane owns 2 z-rows (rows base+lane and
// base+64+lane), streamed through registers in 4 segments of 32 floats.
// Weights in LDS, read as wave-uniform broadcast float4. acc[2][16] per lane,
// zero cross-lane ops. Stores coalesced per h-plane (lane -> consecutive 4B).
// ---------------------------------------------------------------------------
__global__ __launch_bounds__(256)
void pair_bias_kernel(const float* __restrict__ z, const float* __restrict__ wzw,
                      const float* __restrict__ s12, float* __restrict__ bias_out) {
  __shared__ float wlds[16 * DZ];   // 8 KB
  __shared__ float s12l[32];
  const int tid = threadIdx.x;
  {
    const float4* src = reinterpret_cast<const float4*>(wzw);
    float4* dst = reinterpret_cast<float4*>(wlds);
    for (int i = tid; i < (16 * DZ) / 4; i += 256) dst[i] = src[i];
    if (tid < 32) s12l[tid] = s12[tid];
  }
  __syncthreads();

  const int lane = tid & 63;
  const int wv = tid >> 6;
  const int chunk = blockIdx.x * 4 + wv;            // 8192 chunks of 128 rows
  const size_t r0 = (size_t)chunk * 128 + lane;
  const size_t r1 = r0 + 64;

  float acc0[16] = {}, acc1[16] = {};
  float s1a = 0.f, s2a = 0.f, s1b = 0.f, s2b = 0.f;
  const float* zp0 = z + r0 * DZ;
  const float* zp1 = z + r1 * DZ;

#pragma unroll
  for (int seg = 0; seg < 4; ++seg) {
    float4 za[8], zb[8];
#pragma unroll
    for (int qn = 0; qn < 8; ++qn) {
      za[qn] = *reinterpret_cast<const float4*>(zp0 + seg * 32 + qn * 4);
      zb[qn] = *reinterpret_cast<const float4*>(zp1 + seg * 32 + qn * 4);
    }
#pragma unroll
    for (int qn = 0; qn < 8; ++qn) {
      const float4 a = za[qn], b = zb[qn];
      s1a += a.x + a.y + a.z + a.w;
      s2a = fmaf(a.x, a.x, fmaf(a.y, a.y, fmaf(a.z, a.z, fmaf(a.w, a.w, s2a))));
      s1b += b.x + b.y + b.z + b.w;
      s2b = fmaf(b.x, b.x, fmaf(b.y, b.y, fmaf(b.z, b.z, fmaf(b.w, b.w, s2b))));
      const int cbase = seg * 32 + qn * 4;
#pragma unroll
      for (int h = 0; h < 16; ++h) {
        const float4 w4 = *reinterpret_cast<const float4*>(&wlds[h * DZ + cbase]);
        acc0[h] += a.x * w4.x + a.y * w4.y + a.z * w4.z + a.w * w4.w;
        acc1[h] += b.x * w4.x + b.y * w4.y + b.z * w4.z + b.w * w4.w;
      }
    }
  }
  const float mu0 = s1a * (1.f / DZ), mu1 = s1b * (1.f / DZ);
  const float inv0 = rsqrtf(s2a * (1.f / DZ) - mu0 * mu0 + EPS);
  const float inv1 = rsqrtf(s2b * (1.f / DZ) - mu1 * mu1 + EPS);
#pragma unroll
  for (int h = 0; h < 16; ++h) {
    const float S1 = s12l[h], S2 = s12l[16 + h];
    bias_out[(size_t)h * S * S + r0] = inv0 * (acc0[h] - mu0 * S1) + S2;
    bias_out[(size_t)h * S * S + r1] = inv1 * (acc1[h] - mu1 * S1) + S2;
  }
}

// ---------------------------------------------------------------------------
// Flash-style attention. Block = (head h, 64 query rows), 256 threads (16x16).
// ---------------------------------------------------------------------------
__global__ __launch_bounds__(256)
void attn_kernel(const float* __restrict__ q_ws, const float* __restrict__ k_ws,
                 const float* __restrict__ v_ws, const float* __restrict__ bias,
                 float* __restrict__ o_ws) {
  __shared__ float Qs[64][52];   // query rows (scaled), padded
  __shared__ float Ks[64][52];   // key rows, padded
  __shared__ float Vt[48][68];   // V transposed [d][t]
  __shared__ float Ps[64][68];   // probabilities tile

  const int tid = threadIdx.x;
  const int tx = tid & 15, ty = tid >> 4;
  const int h  = blockIdx.x >> 4;
  const int q0 = (blockIdx.x & 15) << 6;
  const float scale = 0.14433756729740643f;  // 1/sqrt(48)

  // stage Q (scaled): 64 rows x 12 float4
#pragma unroll
  for (int i = 0; i < 3; ++i) {
    const int f4 = tid + i * 256;
    const int r = f4 / 12, c4 = f4 % 12;
    float4 v = *reinterpret_cast<const float4*>(q_ws + (size_t)(q0 + r) * D + h * HD + c4 * 4);
    v.x *= scale; v.y *= scale; v.z *= scale; v.w *= scale;
    *reinterpret_cast<float4*>(&Qs[r][c4 * 4]) = v;
  }

  float m[4], l[4] = {0.f, 0.f, 0.f, 0.f};
  float acc[4][3] = {};
#pragma unroll
  for (int i = 0; i < 4; ++i) m[i] = -1e30f;

  for (int t0 = 0; t0 < S; t0 += 64) {
    // stage K tile (rows) and V tile (transposed)
#pragma unroll
    for (int i = 0; i < 3; ++i) {
      const int f4 = tid + i * 256;
      const int r = f4 / 12, c4 = f4 % 12;
      const float4 kv = *reinterpret_cast<const float4*>(k_ws + (size_t)(t0 + r) * D + h * HD + c4 * 4);
      *reinterpret_cast<float4*>(&Ks[r][c4 * 4]) = kv;
      const float4 vv = *reinterpret_cast<const float4*>(v_ws + (size_t)(t0 + r) * D + h * HD + c4 * 4);
      Vt[c4 * 4 + 0][r] = vv.x; Vt[c4 * 4 + 1][r] = vv.y;
      Vt[c4 * 4 + 2][r] = vv.z; Vt[c4 * 4 + 3][r] = vv.w;
    }
    __syncthreads();

    // S-tile: rows 4ty+i, cols 4tx+j, init from bias
    float s4[4][4];
#pragma unroll
    for (int i = 0; i < 4; ++i) {
      const float4 b4 = *reinterpret_cast<const float4*>(
          bias + ((size_t)h * S + (q0 + 4 * ty + i)) * S + t0 + 4 * tx);
      s4[i][0] = b4.x; s4[i][1] = b4.y; s4[i][2] = b4.z; s4[i][3] = b4.w;
    }
#pragma unroll
    for (int k4 = 0; k4 < 12; ++k4) {
      float4 qv[4], kv[4];
#pragma unroll
      for (int i = 0; i < 4; ++i) qv[i] = *reinterpret_cast<const float4*>(&Qs[4 * ty + i][k4 * 4]);
#pragma unroll
      for (int j = 0; j < 4; ++j) kv[j] = *reinterpret_cast<const float4*>(&Ks[4 * tx + j][k4 * 4]);
#pragma unroll
      for (int i = 0; i < 4; ++i)
#pragma unroll
        for (int j = 0; j < 4; ++j)
          s4[i][j] += qv[i].x * kv[j].x + qv[i].y * kv[j].y +
                      qv[i].z * kv[j].z + qv[i].w * kv[j].w;
    }

    // online softmax (row groups = 16 tx lanes; shfl_xor stays in-group)
#pragma unroll
    for (int i = 0; i < 4; ++i) {
      float tmax = fmaxf(fmaxf(s4[i][0], s4[i][1]), fmaxf(s4[i][2], s4[i][3]));
#pragma unroll
      for (int off = 8; off >= 1; off >>= 1) tmax = fmaxf(tmax, __shfl_xor(tmax, off));
      const float mn = fmaxf(m[i], tmax);
      const float fac = __expf(m[i] - mn);
      float p0 = __expf(s4[i][0] - mn), p1 = __expf(s4[i][1] - mn);
      float p2 = __expf(s4[i][2] - mn), p3 = __expf(s4[i][3] - mn);
      l[i] = l[i] * fac + (p0 + p1 + p2 + p3);   // per-thread partial sum
      acc[i][0] *= fac; acc[i][1] *= fac; acc[i][2] *= fac;
      m[i] = mn;
      *reinterpret_cast<float4*>(&Ps[4 * ty + i][4 * tx]) = make_float4(p0, p1, p2, p3);
    }
    __syncthreads();

    // PV: rows 4ty+i, dims 3tx+j, vectorized over t-quads
#pragma unroll
    for (int t4 = 0; t4 < 16; ++t4) {
      float4 pv[4], vv[3];
#pragma unroll
      for (int i = 0; i < 4; ++i) pv[i] = *reinterpret_cast<const float4*>(&Ps[4 * ty + i][4 * t4]);
#pragma unroll
      for (int j = 0; j < 3; ++j) vv[j] = *reinterpret_cast<const float4*>(&Vt[3 * tx + j][4 * t4]);
#pragma unroll
      for (int i = 0; i < 4; ++i)
#pragma unroll
        for (int j = 0; j < 3; ++j)
          acc[i][j] += pv[i].x * vv[j].x + pv[i].y * vv[j].y +
                       pv[i].z * vv[j].z + pv[i].w * vv[j].w;
    }
    __syncthreads();
  }

  // finalize: full row sum of l across tx group, normalize, write
#pragma unroll
  for (int i = 0; i < 4; ++i) {
    float lt = l[i];
#pragma unroll
    for (int off = 8; off >= 1; off >>= 1) lt += __shfl_xor(lt, off);
    const float rl = 1.f / lt;
    float* op = o_ws + (size_t)(q0 + 4 * ty + i) * D + h * HD;
#pragma unroll
    for (int j = 0; j < 3; ++j) op[3 * tx + j] = acc[i][j] * rl;
  }
}

extern "C" void kernel_launch(void* const* d_in, const int* in_sizes, int n_in,
                              void* d_out, int out_size, void* d_ws, size_t ws_size,
                              hipStream_t stream) {
  const float* s    = (const float*)d_in[0];
  const float* z    = (const float*)d_in[1];
  const float* Wq   = (const float*)d_in[2];
  const float* bq   = (const float*)d_in[3];
  const float* Wk   = (const float*)d_in[4];
  const float* Wv   = (const float*)d_in[5];
  const float* Wg   = (const float*)d_in[6];
  const float* ln_w = (const float*)d_in[7];
  const float* ln_b = (const float*)d_in[8];
  const float* Wz   = (const float*)d_in[9];
  const float* Wo   = (const float*)d_in[10];
  float* out = (float*)d_out;

  // workspace (floats): q,k,v,g,o = 5*S*D; bias = H*S*S; wzw = 2048; s12 = 32
  float* q_ws    = (float*)d_ws;
  float* k_ws    = q_ws + (size_t)S * D;
  float* v_ws    = k_ws + (size_t)S * D;
  float* g_ws    = v_ws + (size_t)S * D;
  float* o_ws    = g_ws + (size_t)S * D;
  float* bias_ws = o_ws + (size_t)S * D;
  float* wzw_ws  = bias_ws + (size_t)H * S * S;
  float* s12_ws  = wzw_ws + 16 * DZ;

  // 1) fused QKVG projections
  qkvg_kernel<<<dim3(4 * (D / 64), S / 64), 256, 0, stream>>>(s, Wq, bq, Wk, Wv, Wg, q_ws);
  // 2) pair bias (LN folded): prep then streaming kernel
  pb_prep_kernel<<<1, 256, 0, stream>>>(Wz, ln_w, ln_b, wzw_ws, s12_ws);
  pair_bias_kernel<<<2048, 256, 0, stream>>>(z, wzw_ws, s12_ws, bias_ws);
  // 3) flash attention
  attn_kernel<<<dim3(H * (S / 64)), 256, 0, stream>>>(q_ws, k_ws, v_ws, bias_ws, o_ws);
  // 4) gate + output projection
  outproj_kernel<<<dim3(D / 64, S / 64), 256, 0, stream>>>(o_ws, g_ws, Wo, out);
}